// Round 3
// baseline (115.956 us; speedup 1.0000x reference)
//
#include <hip/hip_runtime.h>

// z[n, i] = m[i] + std_normal[n, i] * (diag_L[i] + JITTER)
// All f32. N = 4096 rows, D = 16384 cols. Pure memory-bound elementwise.
//
// Layout: each thread owns ONE float4 column-group (col = tid & 4095) and
// ROWS_PER_THREAD=8 rows (stride 512 rows apart). m/diag_L loads and the
// column computation hoist out of the loop entirely; the 8 row loads are
// fully unrolled -> 8 outstanding global_load_dwordx4 per thread.
// Nontemporal hints: pure streaming, zero reuse (544 MB >> 32 MB L2).

#define JITTER 1e-6f
#define N_ROWS 4096
#define D4 4096          // D/4 in float4 units
#define ROWS_PER_THREAD 8
#define ROW_GROUPS (N_ROWS / ROWS_PER_THREAD)   // 512
#define STEP ((long long)ROW_GROUPS * D4)       // float4 stride between rows for one thread

typedef float f32x4 __attribute__((ext_vector_type(4)));

__global__ void diag_variational_kernel(const float* __restrict__ m,
                                        const float* __restrict__ diag_L,
                                        const float* __restrict__ std_normal,
                                        float* __restrict__ out) {
    int t = blockIdx.x * blockDim.x + threadIdx.x;   // 0 .. 2,097,151
    int col = t & (D4 - 1);                          // float4 column
    int row0 = t >> 12;                              // 0 .. 511

    // Hoisted per-column broadcast (L2-resident, 64 KiB each)
    const f32x4 mm = ((const f32x4*)m)[col];
    f32x4 dl = ((const f32x4*)diag_L)[col];
    dl += (f32x4)(JITTER);

    const f32x4* sn4 = (const f32x4*)std_normal + (long long)row0 * D4 + col;
    f32x4* o4 = (f32x4*)out + (long long)row0 * D4 + col;

    f32x4 v[ROWS_PER_THREAD];
#pragma unroll
    for (int j = 0; j < ROWS_PER_THREAD; ++j) {
        v[j] = __builtin_nontemporal_load(&sn4[(long long)j * STEP]);
    }
#pragma unroll
    for (int j = 0; j < ROWS_PER_THREAD; ++j) {
        f32x4 z;
        z.x = fmaf(v[j].x, dl.x, mm.x);
        z.y = fmaf(v[j].y, dl.y, mm.y);
        z.z = fmaf(v[j].z, dl.z, mm.z);
        z.w = fmaf(v[j].w, dl.w, mm.w);
        __builtin_nontemporal_store(z, &o4[(long long)j * STEP]);
    }
}

extern "C" void kernel_launch(void* const* d_in, const int* in_sizes, int n_in,
                              void* d_out, int out_size, void* d_ws, size_t ws_size,
                              hipStream_t stream) {
    const float* m = (const float*)d_in[0];
    const float* diag_L = (const float*)d_in[1];
    const float* std_normal = (const float*)d_in[2];
    float* out = (float*)d_out;

    // total threads = D4 * ROW_GROUPS = 4096 * 512 = 2,097,152
    const int block = 256;
    const int grid = (D4 * ROW_GROUPS) / block;  // 8192 blocks

    diag_variational_kernel<<<grid, block, 0, stream>>>(m, diag_L, std_normal, out);
}

// Round 4
// 104.037 us; speedup vs baseline: 1.1146x; 1.1146x over previous
//
#include <hip/hip_runtime.h>

// z[n, i] = m[i] + std_normal[n, i] * (diag_L[i] + JITTER)
// All f32. N = 4096 rows, D = 16384 cols. Pure memory-bound elementwise.
//
// Each thread owns one float4 column (col = t & 4095) and 8 CONSECUTIVE rows.
// m/diag_L broadcast loads hoist out of the loop; 8 fully-unrolled independent
// global_load_dwordx4 per thread (64 KB apart) give deep MLP with compact
// per-block footprint (4 KB wide x 8 rows). Normal (cached) loads/stores —
// nontemporal hints regressed 10% in round 3.

#define JITTER 1e-6f
#define N_ROWS 4096
#define D4 4096          // D/4 in float4 units
#define ROWS_PER_THREAD 8

typedef float f32x4 __attribute__((ext_vector_type(4)));

__global__ void diag_variational_kernel(const float* __restrict__ m,
                                        const float* __restrict__ diag_L,
                                        const float* __restrict__ std_normal,
                                        float* __restrict__ out) {
    int t = blockIdx.x * blockDim.x + threadIdx.x;   // 0 .. 2,097,151
    int col = t & (D4 - 1);                          // float4 column
    int rowgrp = t >> 12;                            // 0 .. 511
    long long row0 = (long long)rowgrp * ROWS_PER_THREAD;

    // Hoisted per-column broadcast (L2-resident, 64 KiB each)
    const f32x4 mm = ((const f32x4*)m)[col];
    f32x4 dl = ((const f32x4*)diag_L)[col];
    dl += (f32x4)(JITTER);

    const f32x4* sn4 = (const f32x4*)std_normal + row0 * D4 + col;
    f32x4* o4 = (f32x4*)out + row0 * D4 + col;

    f32x4 v[ROWS_PER_THREAD];
#pragma unroll
    for (int j = 0; j < ROWS_PER_THREAD; ++j) {
        v[j] = sn4[(long long)j * D4];
    }
#pragma unroll
    for (int j = 0; j < ROWS_PER_THREAD; ++j) {
        f32x4 z;
        z.x = fmaf(v[j].x, dl.x, mm.x);
        z.y = fmaf(v[j].y, dl.y, mm.y);
        z.z = fmaf(v[j].z, dl.z, mm.z);
        z.w = fmaf(v[j].w, dl.w, mm.w);
        o4[(long long)j * D4] = z;
    }
}

extern "C" void kernel_launch(void* const* d_in, const int* in_sizes, int n_in,
                              void* d_out, int out_size, void* d_ws, size_t ws_size,
                              hipStream_t stream) {
    const float* m = (const float*)d_in[0];
    const float* diag_L = (const float*)d_in[1];
    const float* std_normal = (const float*)d_in[2];
    float* out = (float*)d_out;

    // total threads = D4 * (N_ROWS / ROWS_PER_THREAD) = 4096 * 512 = 2,097,152
    const int block = 256;
    const int grid = (D4 * (N_ROWS / ROWS_PER_THREAD)) / block;  // 8192 blocks

    diag_variational_kernel<<<grid, block, 0, stream>>>(m, diag_L, std_normal, out);
}

// Round 5
// 79.720 us; speedup vs baseline: 1.4545x; 1.3050x over previous
//
#include <hip/hip_runtime.h>

// z[n, i] = m[i] + std_normal[n, i] * (diag_L[i] + JITTER)
// All f32. N = 4096 rows, D = 16384 cols. Pure memory-bound elementwise.
//
// Round-4 structure (best so far, 104 us): each thread owns one float4 column
// (col = t & 4095) and 8 consecutive rows; hoisted m/diag_L broadcasts;
// 8 fully-unrolled independent 16B loads. This round: NONTEMPORAL STORES ONLY
// (loads stay cached) — output is write-once/never-read, so skip L2 allocation
// for the write stream. Round 3 confounded NT with a bad stride pattern.

#define JITTER 1e-6f
#define N_ROWS 4096
#define D4 4096          // D/4 in float4 units
#define ROWS_PER_THREAD 8

typedef float f32x4 __attribute__((ext_vector_type(4)));

__global__ void diag_variational_kernel(const float* __restrict__ m,
                                        const float* __restrict__ diag_L,
                                        const float* __restrict__ std_normal,
                                        float* __restrict__ out) {
    int t = blockIdx.x * blockDim.x + threadIdx.x;   // 0 .. 2,097,151
    int col = t & (D4 - 1);                          // float4 column
    int rowgrp = t >> 12;                            // 0 .. 511
    long long row0 = (long long)rowgrp * ROWS_PER_THREAD;

    // Hoisted per-column broadcast (L2-resident, 64 KiB each)
    const f32x4 mm = ((const f32x4*)m)[col];
    f32x4 dl = ((const f32x4*)diag_L)[col];
    dl += (f32x4)(JITTER);

    const f32x4* sn4 = (const f32x4*)std_normal + row0 * D4 + col;
    f32x4* o4 = (f32x4*)out + row0 * D4 + col;

    f32x4 v[ROWS_PER_THREAD];
#pragma unroll
    for (int j = 0; j < ROWS_PER_THREAD; ++j) {
        v[j] = sn4[(long long)j * D4];
    }
#pragma unroll
    for (int j = 0; j < ROWS_PER_THREAD; ++j) {
        f32x4 z;
        z.x = fmaf(v[j].x, dl.x, mm.x);
        z.y = fmaf(v[j].y, dl.y, mm.y);
        z.z = fmaf(v[j].z, dl.z, mm.z);
        z.w = fmaf(v[j].w, dl.w, mm.w);
        __builtin_nontemporal_store(z, &o4[(long long)j * D4]);
    }
}

extern "C" void kernel_launch(void* const* d_in, const int* in_sizes, int n_in,
                              void* d_out, int out_size, void* d_ws, size_t ws_size,
                              hipStream_t stream) {
    const float* m = (const float*)d_in[0];
    const float* diag_L = (const float*)d_in[1];
    const float* std_normal = (const float*)d_in[2];
    float* out = (float*)d_out;

    // total threads = D4 * (N_ROWS / ROWS_PER_THREAD) = 4096 * 512 = 2,097,152
    const int block = 256;
    const int grid = (D4 * (N_ROWS / ROWS_PER_THREAD)) / block;  // 8192 blocks

    diag_variational_kernel<<<grid, block, 0, stream>>>(m, diag_L, std_normal, out);
}